// Round 1
// baseline (394.468 us; speedup 1.0000x reference)
//
#include <hip/hip_runtime.h>
#include <hip/hip_bf16.h>

typedef short bf16x8 __attribute__((ext_vector_type(8)));
typedef float f32x4 __attribute__((ext_vector_type(4)));

#define E_TOTAL 2000000
#define MT 128
#define NTILES (E_TOTAL / MT)   // 15625 exactly

// LDS pitches (in ushort elements); +8 bf16 pad per row -> 2-way bank aliasing (free)
#define XP  136   // X tile: 128 K + 8 pad
#define GP  72    // g tile: 64 K + 8 pad
#define W1P 136
#define B2P 72

__device__ __forceinline__ unsigned short f2bf(float x) {
  __hip_bfloat16 h = __float2bfloat16(x);
  return __builtin_bit_cast(unsigned short, h);
}

// Pre-kernel: bf16 weights into workspace.
// W1g[n*128+k] = bf16(W1[k][n])               (transposed, 64x128)
// B2g[n*64+k]  = bf16(B2[k][n])               (transposed, 80x64)
//   where B2[k][n] = W2[k][n] for n<64, (W2@Wp)[k][n-64] for 64<=n<69, else 0
__global__ void prep_kernel(const float* __restrict__ W1, const float* __restrict__ W2,
                            const float* __restrict__ Wp,
                            unsigned short* __restrict__ W1g,
                            unsigned short* __restrict__ B2g) {
  int t = blockIdx.x * blockDim.x + threadIdx.x;
  int stride = gridDim.x * blockDim.x;
  for (int i = t; i < 64 * 128; i += stride) {
    int n = i >> 7, k = i & 127;
    W1g[i] = f2bf(W1[k * 64 + n]);
  }
  for (int i = t; i < 80 * 64; i += stride) {
    int n = i >> 6, k = i & 63;
    float v;
    if (n < 64) {
      v = W2[k * 64 + n];
    } else if (n < 69) {
      int c = n - 64;
      float s = 0.f;
      for (int j = 0; j < 64; ++j) s += W2[k * 64 + j] * Wp[j * 5 + c];
      v = s;
    } else {
      v = 0.f;
    }
    B2g[i] = f2bf(v);
  }
}

__global__ __launch_bounds__(256, 2)
void mlp_main(const float* __restrict__ ufeat, const float* __restrict__ ifeat,
              const int* __restrict__ src, const int* __restrict__ dst,
              const unsigned short* __restrict__ W1g, const unsigned short* __restrict__ B2g,
              float* __restrict__ out) {
  __shared__ unsigned short Xb[MT * XP];    // 34816 B; aliased as g-tile after GEMM1
  __shared__ unsigned short W1t[64 * W1P];  // 17408 B
  __shared__ unsigned short B2t[80 * B2P];  // 11520 B
  __shared__ int idxLDS[256];               // 1024 B  (total 64768 B)

  const int lid  = threadIdx.x;
  const int lane = lid & 63;
  const int w    = lid >> 6;          // wave 0..3
  const int lr   = lane & 15;         // row/col within 16-tile
  const int lk   = (lane >> 4) << 3;  // k offset 0,8,16,24
  const int tbase = blockIdx.x * MT;

  // ---- stage weights into LDS (16B chunks) ----
  for (int ch = lid; ch < 1024; ch += 256) {           // W1t: 64x128
    int n = ch >> 4, kc = (ch & 15) << 3;
    *reinterpret_cast<bf16x8*>(&W1t[n * W1P + kc]) =
        *reinterpret_cast<const bf16x8*>(&W1g[n * 128 + kc]);
  }
  for (int ch = lid; ch < 640; ch += 256) {            // B2t: 80x64
    int n = ch >> 3, kc = (ch & 7) << 3;
    *reinterpret_cast<bf16x8*>(&B2t[n * B2P + kc]) =
        *reinterpret_cast<const bf16x8*>(&B2g[n * 64 + kc]);
  }
  // ---- edge indices ----
  idxLDS[lid] = (lid < 128) ? src[tbase + lid] : dst[tbase + lid - 128];
  __syncthreads();

  // ---- gather + interleave + bf16-convert into X tile ----
  // 256 rows (128 u-rows then 128 v-rows), 16 lanes cooperate per row (fully coalesced).
  {
    const int c  = lid & 15;   // float4 chunk within row
    const int rb = lid >> 4;
    #pragma unroll
    for (int i = 0; i < 16; ++i) {
      int r    = rb + 16 * i;      // 0..255
      int half = r >> 7;           // 0: u-row, 1: v-row
      int e    = r & 127;
      const float* base = half ? (ifeat + (size_t)idxLDS[r] * 64)
                               : (ufeat + (size_t)idxLDS[r] * 64);
      float4 f = *reinterpret_cast<const float4*>(base + c * 4);
      // element m=4c+i of the 64-vector -> x col = 32*(m/16) + half*16 + (m%16)
      int col = ((c >> 2) * 32) + half * 16 + ((c & 3) * 4);
      ushort4 p;
      p.x = f2bf(f.x); p.y = f2bf(f.y); p.z = f2bf(f.z); p.w = f2bf(f.w);
      *reinterpret_cast<ushort4*>(&Xb[e * XP + col]) = p;
    }
  }
  __syncthreads();

  // ---- GEMM1: C1[128x64] = X[128x128] @ W1 ----
  const f32x4 fz = {0.f, 0.f, 0.f, 0.f};
  f32x4 acc1[2][4];
  #pragma unroll
  for (int mi = 0; mi < 2; ++mi)
    #pragma unroll
    for (int nt = 0; nt < 4; ++nt) acc1[mi][nt] = fz;

  {
    const unsigned short* Xr0 = &Xb[(w * 32 + lr) * XP];
    const unsigned short* Xr1 = Xr0 + 16 * XP;
    #pragma unroll
    for (int kk = 0; kk < 4; ++kk) {
      int ko = kk * 32 + lk;
      bf16x8 a0 = *reinterpret_cast<const bf16x8*>(Xr0 + ko);
      bf16x8 a1 = *reinterpret_cast<const bf16x8*>(Xr1 + ko);
      #pragma unroll
      for (int nt = 0; nt < 4; ++nt) {
        bf16x8 b = *reinterpret_cast<const bf16x8*>(&W1t[(nt * 16 + lr) * W1P + ko]);
        acc1[0][nt] = __builtin_amdgcn_mfma_f32_16x16x32_bf16(a0, b, acc1[0][nt], 0, 0, 0);
        acc1[1][nt] = __builtin_amdgcn_mfma_f32_16x16x32_bf16(a1, b, acc1[1][nt], 0, 0, 0);
      }
    }
  }
  __syncthreads();   // all X reads done; Xb can be reused as g

  // ---- exact GELU, write g (bf16) into aliased LDS ----
  unsigned short* g = Xb;
  const int rbase = (lane >> 4) << 2;   // C-layout row base
  #pragma unroll
  for (int mi = 0; mi < 2; ++mi) {
    int row0 = (2 * w + mi) * 16 + rbase;
    #pragma unroll
    for (int nt = 0; nt < 4; ++nt) {
      f32x4 v = acc1[mi][nt];
      #pragma unroll
      for (int r = 0; r < 4; ++r) {
        float x  = v[r];
        float ge = 0.5f * x * (1.0f + erff(x * 0.70710678118654752f));
        g[(row0 + r) * GP + nt * 16 + lr] = f2bf(ge);
      }
    }
  }
  __syncthreads();

  // ---- GEMM2: C2[128x80] = g[128x64] @ [W2 | W2@Wp | 0] ----
  f32x4 acc2[2][5];
  #pragma unroll
  for (int mi = 0; mi < 2; ++mi)
    #pragma unroll
    for (int nt = 0; nt < 5; ++nt) acc2[mi][nt] = fz;

  #pragma unroll
  for (int kk = 0; kk < 2; ++kk) {
    int ko = kk * 32 + lk;
    bf16x8 a0 = *reinterpret_cast<const bf16x8*>(&g[(w * 32 + lr) * GP + ko]);
    bf16x8 a1 = *reinterpret_cast<const bf16x8*>(&g[(w * 32 + 16 + lr) * GP + ko]);
    #pragma unroll
    for (int nt = 0; nt < 5; ++nt) {
      bf16x8 b = *reinterpret_cast<const bf16x8*>(&B2t[(nt * 16 + lr) * B2P + ko]);
      acc2[0][nt] = __builtin_amdgcn_mfma_f32_16x16x32_bf16(a0, b, acc2[0][nt], 0, 0, 0);
      acc2[1][nt] = __builtin_amdgcn_mfma_f32_16x16x32_bf16(a1, b, acc2[1][nt], 0, 0, 0);
    }
  }

  // ---- epilogue: h_fea = cols 0..63, score = cols 64..68 ----
  float* out_score = out;                 // [E,5]
  float* out_h     = out + 10000000;      // [E,64]
  #pragma unroll
  for (int mi = 0; mi < 2; ++mi) {
    int er0 = tbase + (2 * w + mi) * 16 + rbase;
    #pragma unroll
    for (int nt = 0; nt < 4; ++nt) {
      #pragma unroll
      for (int r = 0; r < 4; ++r)
        out_h[(size_t)(er0 + r) * 64 + nt * 16 + lr] = acc2[mi][nt][r];
    }
    if (lr < 5) {
      #pragma unroll
      for (int r = 0; r < 4; ++r)
        out_score[(size_t)(er0 + r) * 5 + lr] = acc2[mi][4][r];
    }
  }
}

extern "C" void kernel_launch(void* const* d_in, const int* in_sizes, int n_in,
                              void* d_out, int out_size, void* d_ws, size_t ws_size,
                              hipStream_t stream) {
  const float* ufeat = (const float*)d_in[0];
  const float* ifeat = (const float*)d_in[1];
  const float* W1    = (const float*)d_in[2];
  const float* W2    = (const float*)d_in[3];
  const float* Wp    = (const float*)d_in[4];
  const int*   src   = (const int*)d_in[5];
  const int*   dst   = (const int*)d_in[6];

  unsigned short* W1g = (unsigned short*)d_ws;            // 8192 ushorts
  unsigned short* B2g = W1g + 64 * 128;                   // 5120 ushorts

  prep_kernel<<<16, 256, 0, stream>>>(W1, W2, Wp, W1g, B2g);
  mlp_main<<<NTILES, 256, 0, stream>>>(ufeat, ifeat, src, dst, W1g, B2g, (float*)d_out);
}

// Round 2
// 315.396 us; speedup vs baseline: 1.2507x; 1.2507x over previous
//
#include <hip/hip_runtime.h>
#include <hip/hip_bf16.h>

typedef short bf16x8 __attribute__((ext_vector_type(8)));
typedef float f32x4 __attribute__((ext_vector_type(4)));

#define E_TOTAL 2000000
#define MT 128
#define NTILES (E_TOTAL / MT)   // 15625 exactly

// LDS pitches (ushort elements); +8 bf16 pad -> row stride 272B = 68 dwords
// (= 4 mod 32 banks) -> max 2-way aliasing on b128 reads (free, m136)
#define XP  136   // X tile: 128 K + 8 pad
#define GP  72    // g tile alias: 64 K + 8 pad (stride 36 dwords = 4 mod 32)

__device__ __forceinline__ unsigned short f2bf(float x) {
  __hip_bfloat16 h = __float2bfloat16(x);
  return __builtin_bit_cast(unsigned short, h);
}

// Pre-kernel: bf16 weights into workspace.
// W1g[n*128+k] = bf16(W1[k][n])               (transposed, 64x128)
// B2g[n*64+k]  = bf16(B2[k][n])               (transposed, 80x64)
//   where B2[k][n] = W2[k][n] for n<64, (W2@Wp)[k][n-64] for 64<=n<69, else 0
__global__ void prep_kernel(const float* __restrict__ W1, const float* __restrict__ W2,
                            const float* __restrict__ Wp,
                            unsigned short* __restrict__ W1g,
                            unsigned short* __restrict__ B2g) {
  int t = blockIdx.x * blockDim.x + threadIdx.x;
  int stride = gridDim.x * blockDim.x;
  for (int i = t; i < 64 * 128; i += stride) {
    int n = i >> 7, k = i & 127;
    W1g[i] = f2bf(W1[k * 64 + n]);
  }
  for (int i = t; i < 80 * 64; i += stride) {
    int n = i >> 6, k = i & 63;
    float v;
    if (n < 64) {
      v = W2[k * 64 + n];
    } else if (n < 69) {
      int c = n - 64;
      float s = 0.f;
      for (int j = 0; j < 64; ++j) s += W2[k * 64 + j] * Wp[j * 5 + c];
      v = s;
    } else {
      v = 0.f;
    }
    B2g[i] = f2bf(v);
  }
}

__global__ __launch_bounds__(256, 4)
void mlp_main(const float* __restrict__ ufeat, const float* __restrict__ ifeat,
              const int* __restrict__ src, const int* __restrict__ dst,
              const unsigned short* __restrict__ W1g, const unsigned short* __restrict__ B2g,
              float* __restrict__ out) {
  __shared__ unsigned short Xb[MT * XP];    // 34816 B total LDS -> 4 blocks/CU

  const int lid  = threadIdx.x;
  const int lane = lid & 63;
  const int w    = lid >> 6;          // wave 0..3
  const int lr   = lane & 15;         // row/col within 16-tile
  const int lk   = (lane >> 4) << 3;  // k offset 0,8,16,24
  const int tbase = blockIdx.x * MT;

  // ---- load this thread's 16 edge indices straight from global (no LDS, no barrier) ----
  const int c  = lid & 15;   // float4 chunk within row
  const int rb = lid >> 4;
  int eidx[16];
  #pragma unroll
  for (int j = 0; j < 8; ++j) eidx[j]     = src[tbase + rb + 16 * j];
  #pragma unroll
  for (int j = 0; j < 8; ++j) eidx[8 + j] = dst[tbase + rb + 16 * j];

  // ---- gather + interleave + bf16-convert into X tile ----
  // 16 lanes cooperate per row (fully coalesced 256B row reads).
  #pragma unroll
  for (int half = 0; half < 2; ++half) {
    const float* tab = half ? ifeat : ufeat;
    #pragma unroll
    for (int j = 0; j < 8; ++j) {
      int e = rb + 16 * j;
      const float* base = tab + (size_t)eidx[half * 8 + j] * 64 + c * 4;
      float4 f = *reinterpret_cast<const float4*>(base);
      // element m=4c+i of the 64-vector -> x col = 32*(m/16) + half*16 + (m%16)
      int col = ((c >> 2) * 32) + half * 16 + ((c & 3) * 4);
      ushort4 p;
      p.x = f2bf(f.x); p.y = f2bf(f.y); p.z = f2bf(f.z); p.w = f2bf(f.w);
      *reinterpret_cast<ushort4*>(&Xb[e * XP + col]) = p;
    }
  }
  __syncthreads();

  // ---- GEMM1: C1[128x64] = X[128x128] @ W1 ; B-fragments JIT from global (L1-resident) ----
  const f32x4 fz = {0.f, 0.f, 0.f, 0.f};
  f32x4 acc1[2][4];
  #pragma unroll
  for (int mi = 0; mi < 2; ++mi)
    #pragma unroll
    for (int nt = 0; nt < 4; ++nt) acc1[mi][nt] = fz;

  {
    const unsigned short* Xr0 = &Xb[(w * 32 + lr) * XP];
    const unsigned short* Xr1 = Xr0 + 16 * XP;
    #pragma unroll
    for (int kk = 0; kk < 4; ++kk) {
      int ko = kk * 32 + lk;
      bf16x8 a0 = *reinterpret_cast<const bf16x8*>(Xr0 + ko);
      bf16x8 a1 = *reinterpret_cast<const bf16x8*>(Xr1 + ko);
      #pragma unroll
      for (int nt = 0; nt < 4; ++nt) {
        bf16x8 b = *reinterpret_cast<const bf16x8*>(&W1g[(nt * 16 + lr) * 128 + ko]);
        acc1[0][nt] = __builtin_amdgcn_mfma_f32_16x16x32_bf16(a0, b, acc1[0][nt], 0, 0, 0);
        acc1[1][nt] = __builtin_amdgcn_mfma_f32_16x16x32_bf16(a1, b, acc1[1][nt], 0, 0, 0);
      }
    }
  }
  __syncthreads();   // all X reads done; Xb can be reused as g

  // ---- exact GELU, write g (bf16) into aliased LDS ----
  unsigned short* g = Xb;
  const int rbase = (lane >> 4) << 2;   // C-layout row base
  #pragma unroll
  for (int mi = 0; mi < 2; ++mi) {
    int row0 = (2 * w + mi) * 16 + rbase;
    #pragma unroll
    for (int nt = 0; nt < 4; ++nt) {
      f32x4 v = acc1[mi][nt];
      #pragma unroll
      for (int r = 0; r < 4; ++r) {
        float x  = v[r];
        float ge = 0.5f * x * (1.0f + erff(x * 0.70710678118654752f));
        g[(row0 + r) * GP + nt * 16 + lr] = f2bf(ge);
      }
    }
  }
  __syncthreads();

  // ---- GEMM2: C2[128x80] = g[128x64] @ [W2 | W2@Wp | 0] ; B JIT from global ----
  f32x4 acc2[2][5];
  #pragma unroll
  for (int mi = 0; mi < 2; ++mi)
    #pragma unroll
    for (int nt = 0; nt < 5; ++nt) acc2[mi][nt] = fz;

  #pragma unroll
  for (int kk = 0; kk < 2; ++kk) {
    int ko = kk * 32 + lk;
    bf16x8 a0 = *reinterpret_cast<const bf16x8*>(&g[(w * 32 + lr) * GP + ko]);
    bf16x8 a1 = *reinterpret_cast<const bf16x8*>(&g[(w * 32 + 16 + lr) * GP + ko]);
    #pragma unroll
    for (int nt = 0; nt < 5; ++nt) {
      bf16x8 b = *reinterpret_cast<const bf16x8*>(&B2g[(nt * 16 + lr) * 64 + ko]);
      acc2[0][nt] = __builtin_amdgcn_mfma_f32_16x16x32_bf16(a0, b, acc2[0][nt], 0, 0, 0);
      acc2[1][nt] = __builtin_amdgcn_mfma_f32_16x16x32_bf16(a1, b, acc2[1][nt], 0, 0, 0);
    }
  }

  // ---- epilogue: h_fea = cols 0..63, score = cols 64..68 ----
  float* out_score = out;                 // [E,5]
  float* out_h     = out + 10000000;      // [E,64]
  #pragma unroll
  for (int mi = 0; mi < 2; ++mi) {
    int er0 = tbase + (2 * w + mi) * 16 + rbase;
    #pragma unroll
    for (int nt = 0; nt < 4; ++nt) {
      #pragma unroll
      for (int r = 0; r < 4; ++r)
        out_h[(size_t)(er0 + r) * 64 + nt * 16 + lr] = acc2[mi][nt][r];
    }
    if (lr < 5) {
      #pragma unroll
      for (int r = 0; r < 4; ++r)
        out_score[(size_t)(er0 + r) * 5 + lr] = acc2[mi][4][r];
    }
  }
}

extern "C" void kernel_launch(void* const* d_in, const int* in_sizes, int n_in,
                              void* d_out, int out_size, void* d_ws, size_t ws_size,
                              hipStream_t stream) {
  const float* ufeat = (const float*)d_in[0];
  const float* ifeat = (const float*)d_in[1];
  const float* W1    = (const float*)d_in[2];
  const float* W2    = (const float*)d_in[3];
  const float* Wp    = (const float*)d_in[4];
  const int*   src   = (const int*)d_in[5];
  const int*   dst   = (const int*)d_in[6];

  unsigned short* W1g = (unsigned short*)d_ws;            // 8192 ushorts
  unsigned short* B2g = W1g + 64 * 128;                   // 5120 ushorts

  prep_kernel<<<16, 256, 0, stream>>>(W1, W2, Wp, W1g, B2g);
  mlp_main<<<NTILES, 256, 0, stream>>>(ufeat, ifeat, src, dst, W1g, B2g, (float*)d_out);
}